// Round 2
// baseline (5131.957 us; speedup 1.0000x reference)
//
#include <hip/hip_runtime.h>

#define BN 2
#define CI 32
#define CO 64
#define DD 96
#define HH 96
#define WW 96

#define HT 8
#define WT 32
#define COT 8   // co channels per block

__global__ __launch_bounds__(256) void sparse_conv3d_kernel(
    const float* __restrict__ x,      // [B][CI][D][H][W]
    const int*   __restrict__ mask,   // [B][D][H][W]
    const float* __restrict__ wgt,    // [CO][CI][3][3][3]
    const float* __restrict__ bias,   // [CO]
    float*       __restrict__ out)    // [B][CO][D][H][W]
{
    // grid: x = (WW/WT)*(HH/HT) = 3*12 = 36 spatial tiles
    //       y = DD = 96
    //       z = BN * (CO/COT) = 2*8 = 16
    const int tx = threadIdx.x & 31;      // w offset in tile, 0..31
    const int ty = threadIdx.x >> 5;      // h offset in tile, 0..7
    const int tile = blockIdx.x;
    const int w0 = (tile % 3) * WT;
    const int h0 = (tile / 3) * HT;
    const int d  = blockIdx.y;
    const int b  = blockIdx.z >> 3;
    const int cog = blockIdx.z & 7;
    const int co0 = cog * COT;

    __shared__ float sx[3][HT + 2][WT + 2];        // 3*10*34 = 1020 floats
    __shared__ float sw[CI * 27 * COT];            // [(ci*27+k)*COT + c]

    // Stage weights for this co-group, transposed so the 8 co values for a
    // fixed (ci, k) are contiguous (two broadcast float4 reads in the loop).
    for (int i = threadIdx.x; i < CI * 27 * COT; i += 256) {
        int c    = i & (COT - 1);
        int rest = i >> 3;            // ci*27 + k
        int k    = rest % 27;
        int ci   = rest / 27;
        sw[i] = wgt[((co0 + c) * CI + ci) * 27 + k];
    }

    float acc[COT];
    #pragma unroll
    for (int c = 0; c < COT; ++c) acc[c] = 0.f;

    for (int ci = 0; ci < CI; ++ci) {
        __syncthreads();   // protects sw on first iter, sx on later iters
        const float* xb = x + ((size_t)(b * CI + ci)) * (DD * HH * WW);
        for (int i = threadIdx.x; i < 3 * (HT + 2) * (WT + 2); i += 256) {
            int lw = i % (WT + 2);
            int t  = i / (WT + 2);
            int lh = t % (HT + 2);
            int ld = t / (HT + 2);
            int gd = d  + ld - 1;
            int gh = h0 + lh - 1;
            int gw = w0 + lw - 1;
            float v = 0.f;
            if ((unsigned)gd < DD && (unsigned)gh < HH && (unsigned)gw < WW)
                v = xb[(gd * HH + gh) * WW + gw];
            sx[ld][lh][lw] = v;
        }
        __syncthreads();

        #pragma unroll
        for (int kd = 0; kd < 3; ++kd)
        #pragma unroll
        for (int kh = 0; kh < 3; ++kh)
        #pragma unroll
        for (int kw = 0; kw < 3; ++kw) {
            float xv = sx[kd][ty + kh][tx + kw];
            const float4* wp =
                (const float4*)&sw[(ci * 27 + (kd * 3 + kh) * 3 + kw) * COT];
            float4 wa = wp[0];
            float4 wb = wp[1];
            acc[0] += xv * wa.x;  acc[1] += xv * wa.y;
            acc[2] += xv * wa.z;  acc[3] += xv * wa.w;
            acc[4] += xv * wb.x;  acc[5] += xv * wb.y;
            acc[6] += xv * wb.z;  acc[7] += xv * wb.w;
        }
    }

    const int gh = h0 + ty;
    const int gw = w0 + tx;
    const float m = (float)mask[((b * DD + d) * HH + gh) * WW + gw];
    const size_t plane = (size_t)DD * HH * WW;
    size_t obase = (((size_t)(b * CO + co0) * DD + d) * HH + gh) * WW + gw;
    #pragma unroll
    for (int c = 0; c < COT; ++c) {
        out[obase + (size_t)c * plane] = (acc[c] + bias[co0 + c]) * m;
    }
}

extern "C" void kernel_launch(void* const* d_in, const int* in_sizes, int n_in,
                              void* d_out, int out_size, void* d_ws, size_t ws_size,
                              hipStream_t stream) {
    const float* x    = (const float*)d_in[0];
    const int*   mask = (const int*)d_in[1];
    const float* wgt  = (const float*)d_in[2];
    const float* bias = (const float*)d_in[3];
    float* out = (float*)d_out;

    dim3 grid(36, 96, 16);
    dim3 block(256);
    sparse_conv3d_kernel<<<grid, block, 0, stream>>>(x, mask, wgt, bias, out);
}

// Round 3
// 1443.766 us; speedup vs baseline: 3.5546x; 3.5546x over previous
//
#include <hip/hip_runtime.h>

// SparseConv3d: B=2, CI=32, CO=64, K=3, D=H=W=96, SAME pad, out*(mask), +bias.
// Implicit-GEMM with mfma_f32_16x16x32_bf16 (K=32 == CI, no padding waste).
// Block: 8x8 (h,w) tile x 64 co x 24 d-range; 4 waves, wave w computes depth d0+w.
// LDS: weights fragment-packed bf16 (110,592 B) + 6-slice x ring (6*8000 B), 158,592 B total.

typedef short bf16x8 __attribute__((ext_vector_type(8)));
typedef float f32x4 __attribute__((ext_vector_type(4)));

#define DHW (96*96*96)
#define HW  (96*96)
#define WLDS_BYTES 110592   // 27 offsets * 4 coblk * 64 lanes * 16 B
#define SX_BASE    110592
#define SLOT_BYTES 8000     // 100 pos * 80 B (64 B data + 16 B pad -> 5*pos mod 8 chunk swizzle)
#define ROW_BYTES  80

__device__ __forceinline__ ushort rne_bf16(float f) {
    uint u = __float_as_uint(f);
    u += 0x7FFFu + ((u >> 16) & 1u);
    return (ushort)(u >> 16);
}

__global__ __launch_bounds__(256, 1) void conv_mfma(
    const float* __restrict__ x,      // [2][32][96][96][96]
    const int*   __restrict__ mask,   // [2][96][96][96]
    const float* __restrict__ wgt,    // [64][32][3][3][3]
    const float* __restrict__ bias,   // [64]
    float*       __restrict__ out)    // [2][64][96][96][96]
{
    extern __shared__ char smem[];
    ushort* wlds = (ushort*)smem;
    char*   sx   = smem + SX_BASE;

    const int tid  = threadIdx.x;
    const int lane = tid & 63;
    const int wid  = tid >> 6;        // wave id 0..3 -> depth offset
    const int ln   = lane & 15;       // MFMA n-index (co within co-block)
    const int lg   = lane >> 4;       // MFMA k-group (8 ci per group)

    const int bx = blockIdx.x;        // 0..143 hw tiles
    const int th = bx / 12, tw = bx % 12;
    const int h0 = th * 8, w0 = tw * 8;
    const int dlo = blockIdx.y * 24;  // 4 d-ranges
    const int b   = blockIdx.z;

    // ---- stage weights once: fragment-packed bf16 ----
    // wlds flat j = ((o*4 + cb)*64 + l)*8 + e  holds W[co=cb*16+(l&15)][ci=(l>>4)*8+e][o]
    for (int j = tid; j < 27 * 4 * 64 * 8; j += 256) {
        int e  = j & 7;
        int l  = (j >> 3) & 63;
        int cb = (j >> 9) & 3;
        int o  = j >> 11;
        int co = cb * 16 + (l & 15);
        int ci = ((l >> 4) << 3) | e;
        wlds[j] = rne_bf16(wgt[(co * 32 + ci) * 27 + o]);
    }

    float bias_r[4];
    #pragma unroll
    for (int c = 0; c < 4; ++c) bias_r[c] = bias[c * 16 + ln];

    // A-read lane geometry: within an A-tile, pos = l&15 -> (hbit, wl)
    const int hbit = (lane >> 3) & 1;
    const int wl   = lane & 7;
    const int rc0  = hbit * 10 + wl;  // local (lh*10+lw) base, tile t adds 20t

    for (int d0 = dlo; d0 < dlo + 24; d0 += 4) {
        __syncthreads();   // prev compute done (and weight staging on first iter)

        // stage x slices: need input depths [d0-1, d0+4]; reuse 2 from prev step
        int zlo = (d0 == dlo) ? d0 - 1 : d0 + 1;
        for (int zi = zlo; zi <= d0 + 4; ++zi) {
            int slot = (zi + 6) % 6;
            uint* dst = (uint*)(sx + slot * SLOT_BYTES);
            bool zok = (unsigned)zi < 96u;
            for (int j = tid; j < 1600; j += 256) {      // 100 pos * 16 ci-pairs
                int pos = j >> 4, cp = j & 15;
                int lh = pos / 10, lw = pos - lh * 10;
                int gh = h0 - 1 + lh, gw = w0 - 1 + lw;
                uint val = 0;
                if (zok && (unsigned)gh < 96u && (unsigned)gw < 96u) {
                    size_t base = (size_t)(b * 32 + 2 * cp) * DHW + (size_t)zi * HW + gh * 96 + gw;
                    uint u0 = rne_bf16(x[base]);
                    uint u1 = rne_bf16(x[base + DHW]);
                    val = u0 | (u1 << 16);
                }
                dst[(pos * ROW_BYTES + cp * 4) >> 2] = val;
            }
        }
        __syncthreads();

        const int z = d0 + wid;       // this wave's output depth

        f32x4 acc[4][4];
        #pragma unroll
        for (int t = 0; t < 4; ++t)
            #pragma unroll
            for (int c = 0; c < 4; ++c) {
                f32x4 z4 = {0.f, 0.f, 0.f, 0.f};
                acc[t][c] = z4;
            }

        #pragma unroll
        for (int kd = 0; kd < 3; ++kd) {
            const int slot = (z + kd - 1 + 6) % 6;
            const char* slab = sx + slot * SLOT_BYTES;
            #pragma unroll
            for (int kh = 0; kh < 3; ++kh) {
                #pragma unroll
                for (int kw = 0; kw < 3; ++kw) {
                    const int o = (kd * 3 + kh) * 3 + kw;
                    bf16x8 a[4], bb[4];
                    #pragma unroll
                    for (int t = 0; t < 4; ++t) {
                        int pos = rc0 + t * 20 + kh * 10 + kw;
                        a[t] = *(const bf16x8*)(slab + pos * ROW_BYTES + lg * 16);
                    }
                    #pragma unroll
                    for (int c = 0; c < 4; ++c)
                        bb[c] = *(const bf16x8*)((const char*)wlds + (o * 4 + c) * 1024 + lane * 16);
                    #pragma unroll
                    for (int t = 0; t < 4; ++t)
                        #pragma unroll
                        for (int c = 0; c < 4; ++c)
                            acc[t][c] = __builtin_amdgcn_mfma_f32_16x16x32_bf16(
                                a[t], bb[c], acc[t][c], 0, 0, 0);
                }
            }
        }

        // epilogue: D[m][n], m = pos = 16t + 4*lg + r, n = co = 16c + ln
        #pragma unroll
        for (int t = 0; t < 4; ++t) {
            #pragma unroll
            for (int r = 0; r < 4; ++r) {
                int pp = 4 * lg + r;
                int gh = h0 + 2 * t + (pp >> 3);
                int gw = w0 + (pp & 7);
                float mval = (float)mask[(size_t)(b * 96 + z) * HW + gh * 96 + gw];
                #pragma unroll
                for (int c = 0; c < 4; ++c) {
                    int co = c * 16 + ln;
                    size_t oidx = ((size_t)(b * 64 + co) * 96 + z) * HW + gh * 96 + gw;
                    out[oidx] = (acc[t][c][r] + bias_r[c]) * mval;
                }
            }
        }
    }
}

extern "C" void kernel_launch(void* const* d_in, const int* in_sizes, int n_in,
                              void* d_out, int out_size, void* d_ws, size_t ws_size,
                              hipStream_t stream) {
    const float* x    = (const float*)d_in[0];
    const int*   mask = (const int*)d_in[1];
    const float* wgt  = (const float*)d_in[2];
    const float* bias = (const float*)d_in[3];
    float* out = (float*)d_out;

    dim3 grid(144, 4, 2);
    dim3 block(256);
    conv_mfma<<<grid, block, SX_BASE + 6 * SLOT_BYTES, stream>>>(x, mask, wgt, bias, out);
}